// Round 1
// baseline (678.876 us; speedup 1.0000x reference)
//
#include <hip/hip_runtime.h>

// ---- problem constants (from reference) ----
#define NB 2
#define NT 3
#define NCAM 6
#define NC 16
#define FD 48
#define FH 24
#define FW 64
#define GX 100
#define GY 100
#define GZ 8
#define OC 40
#define NVOX (GX * GY * GZ)          // 80000
#define FSZ (FD * FH * FW)           // 73728 voxels per channel volume
#define CAMSZ (NC * FSZ)             // per-camera feature volume (orig layout)
#define BTSZ (NCAM * CAMSZ)          // per-(b,t) feature block (orig layout)
#define HSZ ((size_t)NB * NT * OC * NVOX)             // 19,200,000 elems
#define FT_ELEMS ((size_t)NB * NT * NCAM * FSZ * NC)  // 42,467,328

static __device__ __forceinline__ unsigned short f2bf_rne(float x) {
    unsigned int u = __float_as_uint(x);
    unsigned int r = (u + 0x7fffu + ((u >> 16) & 1u)) >> 16;
    return (unsigned short)r;
}
static __device__ __forceinline__ float bf_lo(unsigned int u) {
    return __uint_as_float(u << 16);
}
static __device__ __forceinline__ float bf_hi(unsigned int u) {
    return __uint_as_float(u & 0xffff0000u);
}

// ----------------------------------------------------------------------------
// Setup: P[b,t,n] = intrins[b] @ RT[b,t,n][:3,:]  (3x4)
//        theta[b,t] cumulative affine (3x4): t=2 -> I, t=1 -> M4[b,1],
//        t=0 -> M4[b,0] @ M4[b,1]
// ----------------------------------------------------------------------------
__global__ void setup_kernel(const float* __restrict__ RT,
                             const float* __restrict__ intrins,
                             const float* __restrict__ DoF,
                             float* __restrict__ P,
                             float* __restrict__ theta) {
    int tid = threadIdx.x;
    if (tid < NB * NT * NCAM) {
        int bt = tid / NCAM;
        int b = bt / NT;
        const float* I3 = intrins + b * 9;
        const float* R = RT + (size_t)tid * 16;
        float* Pp = P + tid * 12;
        for (int r = 0; r < 3; ++r)
            for (int c = 0; c < 4; ++c) {
                float s = 0.f;
                for (int k = 0; k < 3; ++k) s += I3[r * 3 + k] * R[k * 4 + c];
                Pp[r * 4 + c] = s;
            }
    }
    if (tid >= 64 && tid < 64 + NB) {
        int b = tid - 64;
        const float* D0 = DoF + (size_t)(b * NT + 0) * 16;
        const float* D1 = DoF + (size_t)(b * NT + 1) * 16;
        float* th = theta + (size_t)b * NT * 12;
        for (int i = 0; i < 12; ++i) th[2 * 12 + i] = 0.f;
        th[2 * 12 + 0] = 1.f; th[2 * 12 + 5] = 1.f; th[2 * 12 + 10] = 1.f;
        for (int i = 0; i < 12; ++i) th[1 * 12 + i] = D1[i];
        for (int r = 0; r < 3; ++r)
            for (int c = 0; c < 4; ++c) {
                float s = (c == 3) ? D0[r * 4 + 3] : 0.f;
                for (int k = 0; k < 3; ++k) s += D0[r * 4 + k] * D1[k * 4 + c];
                th[0 * 12 + r * 4 + c] = s;
            }
    }
}

// ----------------------------------------------------------------------------
// Transpose features (B,T,N,C,FD,FH,FW) fp32 -> [btn][pos][C16] bf16
// reads coalesced per channel, writes 32B per thread
// ----------------------------------------------------------------------------
__global__ __launch_bounds__(256) void transpose_feat(
    const float* __restrict__ feat, unsigned short* __restrict__ ft) {
    size_t tid = (size_t)blockIdx.x * 256 + threadIdx.x;
    int pos = (int)(tid % FSZ);
    int btn = (int)(tid / FSZ);
    const float* src = feat + (size_t)btn * CAMSZ + pos;
    float v[NC];
#pragma unroll
    for (int c = 0; c < NC; ++c) v[c] = src[(size_t)c * FSZ];
    unsigned int packed[8];
#pragma unroll
    for (int j = 0; j < 8; ++j)
        packed[j] = (unsigned int)f2bf_rne(v[2 * j]) |
                    ((unsigned int)f2bf_rne(v[2 * j + 1]) << 16);
    uint4* dst = reinterpret_cast<uint4*>(ft + ((size_t)btn * FSZ + pos) * NC);
    dst[0] = make_uint4(packed[0], packed[1], packed[2], packed[3]);
    dst[1] = make_uint4(packed[4], packed[5], packed[6], packed[7]);
}

// ----------------------------------------------------------------------------
// Kernel 1: frustum trilinear sample + W_N matvec + ReLU -> h (bf16 chan-last)
// LANE-PAIR SPLIT: even lane of each pair does cams 0-2, odd lane cams 3-5;
// partial acc[40] reduced via __shfl_xor(.,1). Halves the serial gather chain
// per thread and doubles waves in flight (latency-bound kernel).
// h layout: [bt][vid][OC] bf16  (vid = gx*GZ*GY + gz*GY + gy)
// threads: NB*NT*NVOX*2 = 960000 -> 3750 blocks
// ----------------------------------------------------------------------------
template <bool CHLAST>
__global__ __launch_bounds__(256) void sample_mlp1(
    const float* __restrict__ feat,            // original layout (!CHLAST)
    const unsigned short* __restrict__ ft,     // bf16 channel-last (CHLAST)
    const float* __restrict__ P,
    const float* __restrict__ W_N,
    const float* __restrict__ b_N,
    unsigned short* __restrict__ h) {
    int tid = blockIdx.x * 256 + threadIdx.x;
    int half = tid & 1;
    int p = tid >> 1;
    int vid = p % NVOX;
    int bt = p / NVOX;
    int gy = vid % GY;
    int r2 = vid / GY;
    int gz = r2 % GZ;
    int gx = r2 / GZ;
    float X = (float)gx - 49.5f;
    float Y = (float)gy - 49.5f;
    float Z = (float)gz - 2.5f;

    float acc[OC];
#pragma unroll
    for (int o = 0; o < OC; ++o) acc[o] = half ? 0.f : b_N[o];

#pragma unroll
    for (int nn = 0; nn < 3; ++nn) {
        int n = half * 3 + nn;
        const float* Pp = P + (bt * NCAM + n) * 12;
        float px = Pp[0] * X + Pp[1] * Y + Pp[2] * Z + Pp[3];
        float py = Pp[4] * X + Pp[5] * Y + Pp[6] * Z + Pp[7];
        float pz = Pp[8] * X + Pp[9] * Y + Pp[10] * Z + Pp[11];
        float zc = fmaxf(pz, 1e-5f);
        float ix = px / zc;                       // = u (normalization round-trips)
        float iy = py / zc;
        float iz = (pz - 2.0f) * (48.0f / 44.8f); // = dbin
        float x0 = floorf(ix), y0 = floorf(iy), z0 = floorf(iz);
        float wx1 = ix - x0, wy1 = iy - y0, wz1 = iz - z0;
        float wx0 = 1.f - wx1, wy0 = 1.f - wy1, wz0 = 1.f - wz1;

        float w8[8];
        int off8[8];
#pragma unroll
        for (int k = 0; k < 8; ++k) {
            float xf = x0 + (float)(k & 1);
            float yf = y0 + (float)((k >> 1) & 1);
            float zf = z0 + (float)(k >> 2);
            bool valid = (xf >= 0.f) & (xf <= (float)(FW - 1)) &
                         (yf >= 0.f) & (yf <= (float)(FH - 1)) &
                         (zf >= 0.f) & (zf <= (float)(FD - 1));
            int xi = (int)fminf(fmaxf(xf, 0.f), (float)(FW - 1));
            int yi = (int)fminf(fmaxf(yf, 0.f), (float)(FH - 1));
            int zi = (int)fminf(fmaxf(zf, 0.f), (float)(FD - 1));
            float w = ((k & 1) ? wx1 : wx0) * (((k >> 1) & 1) ? wy1 : wy0) *
                      ((k >> 2) ? wz1 : wz0);
            w8[k] = valid ? w : 0.f;
            off8[k] = (zi * FH + yi) * FW + xi;
        }

        float s[NC];
#pragma unroll
        for (int c = 0; c < NC; ++c) s[c] = 0.f;

        if constexpr (CHLAST) {
            const size_t camBase = (size_t)(bt * NCAM + n) * FSZ;
#pragma unroll
            for (int k = 0; k < 8; ++k) {
                float w = w8[k];
                const uint4* cp = reinterpret_cast<const uint4*>(
                    ft + (camBase + (size_t)off8[k]) * NC);
                uint4 a = cp[0], b2 = cp[1];
                unsigned int uu[8] = {a.x, a.y, a.z, a.w, b2.x, b2.y, b2.z, b2.w};
#pragma unroll
                for (int j = 0; j < 8; ++j) {
                    s[2 * j + 0] = fmaf(w, bf_lo(uu[j]), s[2 * j + 0]);
                    s[2 * j + 1] = fmaf(w, bf_hi(uu[j]), s[2 * j + 1]);
                }
            }
        } else {
            const float* fn = feat + (size_t)bt * BTSZ + (size_t)n * CAMSZ;
#pragma unroll
            for (int c = 0; c < NC; ++c) {
                const float* fc = fn + (size_t)c * FSZ;
                float v = 0.f;
#pragma unroll
                for (int k = 0; k < 8; ++k) v = fmaf(w8[k], fc[off8[k]], v);
                s[c] = v;
            }
        }

        // acc[o] += W_N[o, n*16 + c] * s[c]
#pragma unroll
        for (int o = 0; o < OC; ++o) {
            const float4* w4 =
                reinterpret_cast<const float4*>(W_N + o * (NCAM * NC) + n * NC);
#pragma unroll
            for (int q = 0; q < 4; ++q) {
                float4 w = w4[q];
                acc[o] = fmaf(w.x, s[4 * q + 0], acc[o]);
                acc[o] = fmaf(w.y, s[4 * q + 1], acc[o]);
                acc[o] = fmaf(w.z, s[4 * q + 2], acc[o]);
                acc[o] = fmaf(w.w, s[4 * q + 3], acc[o]);
            }
        }
    }

    // pair reduction: both lanes end with the full 40-ch result
#pragma unroll
    for (int o = 0; o < OC; ++o) acc[o] += __shfl_xor(acc[o], 1);

    // ReLU + pack to bf16; even lane stores ch 0..15 (32B), odd ch 16..39 (48B)
    unsigned short* dst = h + ((size_t)bt * NVOX + (size_t)vid) * OC;
    if (half == 0) {
        unsigned int u[8];
#pragma unroll
        for (int j = 0; j < 8; ++j)
            u[j] = (unsigned int)f2bf_rne(fmaxf(acc[2 * j], 0.f)) |
                   ((unsigned int)f2bf_rne(fmaxf(acc[2 * j + 1], 0.f)) << 16);
        uint4* d4 = reinterpret_cast<uint4*>(dst);
        d4[0] = make_uint4(u[0], u[1], u[2], u[3]);
        d4[1] = make_uint4(u[4], u[5], u[6], u[7]);
    } else {
        unsigned int u[12];
#pragma unroll
        for (int j = 0; j < 12; ++j)
            u[j] = (unsigned int)f2bf_rne(fmaxf(acc[16 + 2 * j], 0.f)) |
                   ((unsigned int)f2bf_rne(fmaxf(acc[16 + 2 * j + 1], 0.f)) << 16);
        uint4* d4 = reinterpret_cast<uint4*>(dst + 16);  // +32B, 16B-aligned
        d4[0] = make_uint4(u[0], u[1], u[2], u[3]);
        d4[1] = make_uint4(u[4], u[5], u[6], u[7]);
        d4[2] = make_uint4(u[8], u[9], u[10], u[11]);
    }
}

// ----------------------------------------------------------------------------
// Kernel 2: temporal affine warp (trilinear on bf16 channel-last h) + W_T + ReLU
// LANE-PAIR SPLIT: even lane handles t=0, odd lane t=1 (full 8-corner sample);
// t=2 has theta == I (identity grid, align_corners) -> exact pass-through, so
// it is a single direct 80B load, matvec split across the pair.
// out layout: [b][o][d][h][w] = (B,40,100,8,100)
// threads: NB*NVOX*2 = 320000 -> 1250 blocks
// ----------------------------------------------------------------------------
__global__ __launch_bounds__(256) void warp_mlp2(
    const unsigned short* __restrict__ h,
    const float* __restrict__ theta,
    const float* __restrict__ W_T,
    const float* __restrict__ b_T,
    float* __restrict__ out) {
    int tid = blockIdx.x * 256 + threadIdx.x;
    int half = tid & 1;
    int p = tid >> 1;
    int vid = p % NVOX;
    int b = p / NVOX;
    int w_ = vid % GY;        // Wp = 100
    int r2 = vid / GY;
    int h_ = r2 % GZ;         // Hp = 8
    int d_ = r2 / GZ;         // Dp = 100

    float xg = -1.f + 2.f * (float)w_ / 99.f;
    float yg = -1.f + 2.f * (float)h_ / 7.f;
    float zg = -1.f + 2.f * (float)d_ / 99.f;

    float acc[OC];
#pragma unroll
    for (int o = 0; o < OC; ++o) acc[o] = half ? 0.f : b_T[o];

    // ---- gather-sampled term: t = half (0 or 1) ----
    {
        int t = half;
        const float* th = theta + (b * NT + t) * 12;
        float g0 = th[0] * xg + th[1] * yg + th[2] * zg + th[3];
        float g1 = th[4] * xg + th[5] * yg + th[6] * zg + th[7];
        float g2 = th[8] * xg + th[9] * yg + th[10] * zg + th[11];
        float ix = (g0 + 1.f) * 0.5f * 99.f;
        float iy = (g1 + 1.f) * 0.5f * 7.f;
        float iz = (g2 + 1.f) * 0.5f * 99.f;
        float x0 = floorf(ix), y0 = floorf(iy), z0 = floorf(iz);
        float wx1 = ix - x0, wy1 = iy - y0, wz1 = iz - z0;
        float wx0 = 1.f - wx1, wy0 = 1.f - wy1, wz0 = 1.f - wz1;

        float w8[8];
        int off8[8];
#pragma unroll
        for (int k = 0; k < 8; ++k) {
            float xf = x0 + (float)(k & 1);
            float yf = y0 + (float)((k >> 1) & 1);
            float zf = z0 + (float)(k >> 2);
            bool valid = (xf >= 0.f) & (xf <= 99.f) &
                         (yf >= 0.f) & (yf <= 7.f) &
                         (zf >= 0.f) & (zf <= 99.f);
            int xi = (int)fminf(fmaxf(xf, 0.f), 99.f);
            int yi = (int)fminf(fmaxf(yf, 0.f), 7.f);
            int zi = (int)fminf(fmaxf(zf, 0.f), 99.f);
            float w = ((k & 1) ? wx1 : wx0) * (((k >> 1) & 1) ? wy1 : wy0) *
                      ((k >> 2) ? wz1 : wz0);
            w8[k] = valid ? w : 0.f;
            off8[k] = (zi * GZ + yi) * GY + xi;  // voxel index in [vid] space
        }

        const unsigned short* hb = h + (size_t)(b * NT + t) * NVOX * OC;
        float sval[OC];
#pragma unroll
        for (int o2 = 0; o2 < OC; ++o2) sval[o2] = 0.f;
#pragma unroll
        for (int k = 0; k < 8; ++k) {
            float w = w8[k];
            const uint4* cp =
                reinterpret_cast<const uint4*>(hb + (size_t)off8[k] * OC);
            uint4 a0 = cp[0], a1 = cp[1], a2 = cp[2], a3 = cp[3], a4 = cp[4];
            unsigned int uu[20] = {a0.x, a0.y, a0.z, a0.w, a1.x, a1.y, a1.z, a1.w,
                                   a2.x, a2.y, a2.z, a2.w, a3.x, a3.y, a3.z, a3.w,
                                   a4.x, a4.y, a4.z, a4.w};
#pragma unroll
            for (int j = 0; j < 20; ++j) {
                sval[2 * j + 0] = fmaf(w, bf_lo(uu[j]), sval[2 * j + 0]);
                sval[2 * j + 1] = fmaf(w, bf_hi(uu[j]), sval[2 * j + 1]);
            }
        }

        // acc[o] += W_T[o, t*40 + o2] * sval[o2]
#pragma unroll
        for (int o = 0; o < OC; ++o) {
            const float4* w4 =
                reinterpret_cast<const float4*>(W_T + o * (NT * OC) + t * OC);
#pragma unroll
            for (int q = 0; q < 10; ++q) {
                float4 w = w4[q];
                acc[o] = fmaf(w.x, sval[4 * q + 0], acc[o]);
                acc[o] = fmaf(w.y, sval[4 * q + 1], acc[o]);
                acc[o] = fmaf(w.z, sval[4 * q + 2], acc[o]);
                acc[o] = fmaf(w.w, sval[4 * q + 3], acc[o]);
            }
        }
    }

    // ---- t=2: identity grid -> direct load, matvec split across the pair ----
    {
        const unsigned short* hb2 =
            h + ((size_t)(b * NT + 2) * NVOX + (size_t)vid) * OC;
        if (half == 0) {
            // channels 0..15
            const uint4* cp = reinterpret_cast<const uint4*>(hb2);
            uint4 a0 = cp[0], a1 = cp[1];
            unsigned int uu[8] = {a0.x, a0.y, a0.z, a0.w, a1.x, a1.y, a1.z, a1.w};
            float sv[16];
#pragma unroll
            for (int j = 0; j < 8; ++j) {
                sv[2 * j + 0] = bf_lo(uu[j]);
                sv[2 * j + 1] = bf_hi(uu[j]);
            }
#pragma unroll
            for (int o = 0; o < OC; ++o) {
                const float4* w4 =
                    reinterpret_cast<const float4*>(W_T + o * (NT * OC) + 2 * OC);
#pragma unroll
                for (int q = 0; q < 4; ++q) {
                    float4 w = w4[q];
                    acc[o] = fmaf(w.x, sv[4 * q + 0], acc[o]);
                    acc[o] = fmaf(w.y, sv[4 * q + 1], acc[o]);
                    acc[o] = fmaf(w.z, sv[4 * q + 2], acc[o]);
                    acc[o] = fmaf(w.w, sv[4 * q + 3], acc[o]);
                }
            }
        } else {
            // channels 16..39 (start at +32B: 16B-aligned)
            const uint4* cp = reinterpret_cast<const uint4*>(hb2 + 16);
            uint4 a0 = cp[0], a1 = cp[1], a2 = cp[2];
            unsigned int uu[12] = {a0.x, a0.y, a0.z, a0.w, a1.x, a1.y,
                                   a1.z, a1.w, a2.x, a2.y, a2.z, a2.w};
            float sv[24];
#pragma unroll
            for (int j = 0; j < 12; ++j) {
                sv[2 * j + 0] = bf_lo(uu[j]);
                sv[2 * j + 1] = bf_hi(uu[j]);
            }
#pragma unroll
            for (int o = 0; o < OC; ++o) {
                const float4* w4 = reinterpret_cast<const float4*>(
                    W_T + o * (NT * OC) + 2 * OC + 16);
#pragma unroll
                for (int q = 0; q < 6; ++q) {
                    float4 w = w4[q];
                    acc[o] = fmaf(w.x, sv[4 * q + 0], acc[o]);
                    acc[o] = fmaf(w.y, sv[4 * q + 1], acc[o]);
                    acc[o] = fmaf(w.z, sv[4 * q + 2], acc[o]);
                    acc[o] = fmaf(w.w, sv[4 * q + 3], acc[o]);
                }
            }
        }
    }

    // pair reduction: both lanes end with the full 40-ch result
#pragma unroll
    for (int o = 0; o < OC; ++o) acc[o] += __shfl_xor(acc[o], 1);

    // even lane stores o=0..19, odd o=20..39; per-o planes stay coalesced
    float* op = out + (size_t)b * OC * NVOX + vid;
    int obase = half * 20;
#pragma unroll
    for (int j = 0; j < 20; ++j)
        op[(size_t)(obase + j) * NVOX] = fmaxf(acc[obase + j], 0.f);
}

extern "C" void kernel_launch(void* const* d_in, const int* in_sizes, int n_in,
                              void* d_out, int out_size, void* d_ws, size_t ws_size,
                              hipStream_t stream) {
    const float* frustum = (const float*)d_in[0];
    const float* RT      = (const float*)d_in[1];
    const float* intrins = (const float*)d_in[2];
    const float* DoF     = (const float*)d_in[3];
    const float* W_N     = (const float*)d_in[4];
    const float* b_N     = (const float*)d_in[5];
    const float* W_T     = (const float*)d_in[6];
    const float* b_T     = (const float*)d_in[7];
    float* out = (float*)d_out;

    const size_t ft_bytes = FT_ELEMS * sizeof(unsigned short); // ~85 MB
    const size_t h_bytes  = HSZ * sizeof(unsigned short);      // ~38.4 MB
    const size_t small = 4096;                                 // P + theta

    char* base = (char*)d_ws;
    bool use_ft = ws_size >= ft_bytes + h_bytes + small;

    size_t ft_al = use_ft ? ((ft_bytes + 255) & ~(size_t)255) : 0;
    unsigned short* ft_buf = (unsigned short*)base;
    unsigned short* h_buf = (unsigned short*)(base + ft_al);
    float* P_buf = (float*)(base + ft_al + ((h_bytes + 255) & ~(size_t)255));
    float* th_buf = P_buf + NB * NT * NCAM * 12;

    setup_kernel<<<1, 128, 0, stream>>>(RT, intrins, DoF, P_buf, th_buf);

    const int tr_blocks = (NB * NT * NCAM * FSZ) / 256;      // 10368
    const int n1_blocks = (NB * NT * NVOX * 2) / 256;        // 3750
    const int n2_blocks = (NB * NVOX * 2) / 256;             // 1250

    if (use_ft) {
        transpose_feat<<<tr_blocks, 256, 0, stream>>>(frustum, ft_buf);
        sample_mlp1<true><<<n1_blocks, 256, 0, stream>>>(
            frustum, ft_buf, P_buf, W_N, b_N, h_buf);
    } else {
        sample_mlp1<false><<<n1_blocks, 256, 0, stream>>>(
            frustum, (const unsigned short*)nullptr, P_buf, W_N, b_N, h_buf);
    }

    warp_mlp2<<<n2_blocks, 256, 0, stream>>>(h_buf, th_buf, W_T, b_T, out);
}

// Round 2
// 577.412 us; speedup vs baseline: 1.1757x; 1.1757x over previous
//
#include <hip/hip_runtime.h>

// ---- problem constants (from reference) ----
#define NB 2
#define NT 3
#define NCAM 6
#define NC 16
#define FD 48
#define FH 24
#define FW 64
#define GX 100
#define GY 100
#define GZ 8
#define OC 40
#define NVOX (GX * GY * GZ)          // 80000
#define FSZ (FD * FH * FW)           // 73728 voxels per channel volume
#define CAMSZ (NC * FSZ)             // per-camera feature volume (orig layout)
#define BTSZ (NCAM * CAMSZ)          // per-(b,t) feature block (orig layout)
#define HSZ ((size_t)NB * NT * OC * NVOX)             // 19,200,000 elems
#define FT_ELEMS ((size_t)NB * NT * NCAM * FSZ * NC)  // 42,467,328

static __device__ __forceinline__ unsigned short f2bf_rne(float x) {
    unsigned int u = __float_as_uint(x);
    unsigned int r = (u + 0x7fffu + ((u >> 16) & 1u)) >> 16;
    return (unsigned short)r;
}
static __device__ __forceinline__ float bf_lo(unsigned int u) {
    return __uint_as_float(u << 16);
}
static __device__ __forceinline__ float bf_hi(unsigned int u) {
    return __uint_as_float(u & 0xffff0000u);
}

// ----------------------------------------------------------------------------
// Setup: P[b,t,n] = intrins[b] @ RT[b,t,n][:3,:]  (3x4)
//        theta[b,t] cumulative affine (3x4): t=2 -> I, t=1 -> M4[b,1],
//        t=0 -> M4[b,0] @ M4[b,1]
// ----------------------------------------------------------------------------
__global__ void setup_kernel(const float* __restrict__ RT,
                             const float* __restrict__ intrins,
                             const float* __restrict__ DoF,
                             float* __restrict__ P,
                             float* __restrict__ theta) {
    int tid = threadIdx.x;
    if (tid < NB * NT * NCAM) {
        int bt = tid / NCAM;
        int b = bt / NT;
        const float* I3 = intrins + b * 9;
        const float* R = RT + (size_t)tid * 16;
        float* Pp = P + tid * 12;
        for (int r = 0; r < 3; ++r)
            for (int c = 0; c < 4; ++c) {
                float s = 0.f;
                for (int k = 0; k < 3; ++k) s += I3[r * 3 + k] * R[k * 4 + c];
                Pp[r * 4 + c] = s;
            }
    }
    if (tid >= 64 && tid < 64 + NB) {
        int b = tid - 64;
        const float* D0 = DoF + (size_t)(b * NT + 0) * 16;
        const float* D1 = DoF + (size_t)(b * NT + 1) * 16;
        float* th = theta + (size_t)b * NT * 12;
        for (int i = 0; i < 12; ++i) th[2 * 12 + i] = 0.f;
        th[2 * 12 + 0] = 1.f; th[2 * 12 + 5] = 1.f; th[2 * 12 + 10] = 1.f;
        for (int i = 0; i < 12; ++i) th[1 * 12 + i] = D1[i];
        for (int r = 0; r < 3; ++r)
            for (int c = 0; c < 4; ++c) {
                float s = (c == 3) ? D0[r * 4 + 3] : 0.f;
                for (int k = 0; k < 3; ++k) s += D0[r * 4 + k] * D1[k * 4 + c];
                th[0 * 12 + r * 4 + c] = s;
            }
    }
}

// ----------------------------------------------------------------------------
// Transpose features (B,T,N,C,FD,FH,FW) fp32 -> [btn][pos][C16] bf16
// reads coalesced per channel, writes 32B per thread
// ----------------------------------------------------------------------------
__global__ __launch_bounds__(256) void transpose_feat(
    const float* __restrict__ feat, unsigned short* __restrict__ ft) {
    size_t tid = (size_t)blockIdx.x * 256 + threadIdx.x;
    int pos = (int)(tid % FSZ);
    int btn = (int)(tid / FSZ);
    const float* src = feat + (size_t)btn * CAMSZ + pos;
    float v[NC];
#pragma unroll
    for (int c = 0; c < NC; ++c) v[c] = src[(size_t)c * FSZ];
    unsigned int packed[8];
#pragma unroll
    for (int j = 0; j < 8; ++j)
        packed[j] = (unsigned int)f2bf_rne(v[2 * j]) |
                    ((unsigned int)f2bf_rne(v[2 * j + 1]) << 16);
    uint4* dst = reinterpret_cast<uint4*>(ft + ((size_t)btn * FSZ + pos) * NC);
    dst[0] = make_uint4(packed[0], packed[1], packed[2], packed[3]);
    dst[1] = make_uint4(packed[4], packed[5], packed[6], packed[7]);
}

// ----------------------------------------------------------------------------
// Kernel 1: frustum trilinear sample (6 cams x 16 ch) + W_N matvec + ReLU -> h
// ROUND-0 STRUCTURE (one thread per (b,t,voxel), sequential 6-cam loop): the
// compiler batches a whole corner-gather (16 loads) in flight. Lane-pair split
// regressed 2x (VGPR 60->48 starved load batching) -- do not reintroduce.
// bf16 ft gather (32B/corner) + bf16 h store (80B/thread).
// h layout: [bt][vid][OC] bf16  (vid = gx*GZ*GY + gz*GY + gy)
// ----------------------------------------------------------------------------
template <bool CHLAST>
__global__ __launch_bounds__(256) void sample_mlp1(
    const float* __restrict__ feat,            // original layout (!CHLAST)
    const unsigned short* __restrict__ ft,     // bf16 channel-last (CHLAST)
    const float* __restrict__ P,
    const float* __restrict__ W_N,
    const float* __restrict__ b_N,
    unsigned short* __restrict__ h) {
    int tid = blockIdx.x * 256 + threadIdx.x;
    int vid = tid % NVOX;
    int bt = tid / NVOX;
    int gy = vid % GY;
    int r2 = vid / GY;
    int gz = r2 % GZ;
    int gx = r2 / GZ;
    float X = (float)gx - 49.5f;
    float Y = (float)gy - 49.5f;
    float Z = (float)gz - 2.5f;

    float acc[OC];
#pragma unroll
    for (int o = 0; o < OC; ++o) acc[o] = b_N[o];

    for (int n = 0; n < NCAM; ++n) {
        const float* Pp = P + (bt * NCAM + n) * 12;
        float px = Pp[0] * X + Pp[1] * Y + Pp[2] * Z + Pp[3];
        float py = Pp[4] * X + Pp[5] * Y + Pp[6] * Z + Pp[7];
        float pz = Pp[8] * X + Pp[9] * Y + Pp[10] * Z + Pp[11];
        float zc = fmaxf(pz, 1e-5f);
        float ix = px / zc;                       // = u (normalization round-trips)
        float iy = py / zc;
        float iz = (pz - 2.0f) * (48.0f / 44.8f); // = dbin
        float x0 = floorf(ix), y0 = floorf(iy), z0 = floorf(iz);
        float wx1 = ix - x0, wy1 = iy - y0, wz1 = iz - z0;
        float wx0 = 1.f - wx1, wy0 = 1.f - wy1, wz0 = 1.f - wz1;

        float w8[8];
        int off8[8];
#pragma unroll
        for (int k = 0; k < 8; ++k) {
            float xf = x0 + (float)(k & 1);
            float yf = y0 + (float)((k >> 1) & 1);
            float zf = z0 + (float)(k >> 2);
            bool valid = (xf >= 0.f) & (xf <= (float)(FW - 1)) &
                         (yf >= 0.f) & (yf <= (float)(FH - 1)) &
                         (zf >= 0.f) & (zf <= (float)(FD - 1));
            int xi = (int)fminf(fmaxf(xf, 0.f), (float)(FW - 1));
            int yi = (int)fminf(fmaxf(yf, 0.f), (float)(FH - 1));
            int zi = (int)fminf(fmaxf(zf, 0.f), (float)(FD - 1));
            float w = ((k & 1) ? wx1 : wx0) * (((k >> 1) & 1) ? wy1 : wy0) *
                      ((k >> 2) ? wz1 : wz0);
            w8[k] = valid ? w : 0.f;
            off8[k] = (zi * FH + yi) * FW + xi;
        }

        float s[NC];
#pragma unroll
        for (int c = 0; c < NC; ++c) s[c] = 0.f;

        if constexpr (CHLAST) {
            const size_t camBase = (size_t)(bt * NCAM + n) * FSZ;
#pragma unroll
            for (int k = 0; k < 8; ++k) {
                float w = w8[k];
                const uint4* cp = reinterpret_cast<const uint4*>(
                    ft + (camBase + (size_t)off8[k]) * NC);
                uint4 a = cp[0], b2 = cp[1];
                unsigned int uu[8] = {a.x, a.y, a.z, a.w, b2.x, b2.y, b2.z, b2.w};
#pragma unroll
                for (int j = 0; j < 8; ++j) {
                    s[2 * j + 0] = fmaf(w, bf_lo(uu[j]), s[2 * j + 0]);
                    s[2 * j + 1] = fmaf(w, bf_hi(uu[j]), s[2 * j + 1]);
                }
            }
        } else {
            const float* fn = feat + (size_t)bt * BTSZ + (size_t)n * CAMSZ;
#pragma unroll
            for (int c = 0; c < NC; ++c) {
                const float* fc = fn + (size_t)c * FSZ;
                float v = 0.f;
#pragma unroll
                for (int k = 0; k < 8; ++k) v = fmaf(w8[k], fc[off8[k]], v);
                s[c] = v;
            }
        }

        // acc[o] += W_N[o, n*16 + c] * s[c]
#pragma unroll
        for (int o = 0; o < OC; ++o) {
            const float4* w4 =
                reinterpret_cast<const float4*>(W_N + o * (NCAM * NC) + n * NC);
#pragma unroll
            for (int q = 0; q < 4; ++q) {
                float4 w = w4[q];
                acc[o] = fmaf(w.x, s[4 * q + 0], acc[o]);
                acc[o] = fmaf(w.y, s[4 * q + 1], acc[o]);
                acc[o] = fmaf(w.z, s[4 * q + 2], acc[o]);
                acc[o] = fmaf(w.w, s[4 * q + 3], acc[o]);
            }
        }
    }

    // ReLU + pack to bf16, store 80B (5 x uint4)
    unsigned int u[20];
#pragma unroll
    for (int j = 0; j < 20; ++j)
        u[j] = (unsigned int)f2bf_rne(fmaxf(acc[2 * j], 0.f)) |
               ((unsigned int)f2bf_rne(fmaxf(acc[2 * j + 1], 0.f)) << 16);
    uint4* d4 = reinterpret_cast<uint4*>(
        h + ((size_t)bt * NVOX + (size_t)vid) * OC);
#pragma unroll
    for (int q = 0; q < 5; ++q)
        d4[q] = make_uint4(u[4 * q], u[4 * q + 1], u[4 * q + 2], u[4 * q + 3]);
}

// ----------------------------------------------------------------------------
// Kernel 2: temporal affine warp (trilinear on bf16 channel-last h) + W_T + ReLU
// ROUND-0 STRUCTURE (one thread per (b,voxel), sequential t loop, no lane
// split). t=2 has theta == I (identity grid, align_corners) -> exact
// pass-through: single 80B load instead of an 8-corner gather.
// out layout: [b][o][d][h][w] = (B,40,100,8,100)
// ----------------------------------------------------------------------------
__global__ __launch_bounds__(256) void warp_mlp2(
    const unsigned short* __restrict__ h,
    const float* __restrict__ theta,
    const float* __restrict__ W_T,
    const float* __restrict__ b_T,
    float* __restrict__ out) {
    int tid = blockIdx.x * 256 + threadIdx.x;
    int vid = tid % NVOX;
    int b = tid / NVOX;
    int w_ = vid % GY;        // Wp = 100
    int r2 = vid / GY;
    int h_ = r2 % GZ;         // Hp = 8
    int d_ = r2 / GZ;         // Dp = 100

    float xg = -1.f + 2.f * (float)w_ / 99.f;
    float yg = -1.f + 2.f * (float)h_ / 7.f;
    float zg = -1.f + 2.f * (float)d_ / 99.f;

    float acc[OC];
#pragma unroll
    for (int o = 0; o < OC; ++o) acc[o] = b_T[o];

    // ---- t = 0, 1: full trilinear gather ----
    for (int t = 0; t < 2; ++t) {
        const float* th = theta + (b * NT + t) * 12;
        float g0 = th[0] * xg + th[1] * yg + th[2] * zg + th[3];
        float g1 = th[4] * xg + th[5] * yg + th[6] * zg + th[7];
        float g2 = th[8] * xg + th[9] * yg + th[10] * zg + th[11];
        float ix = (g0 + 1.f) * 0.5f * 99.f;
        float iy = (g1 + 1.f) * 0.5f * 7.f;
        float iz = (g2 + 1.f) * 0.5f * 99.f;
        float x0 = floorf(ix), y0 = floorf(iy), z0 = floorf(iz);
        float wx1 = ix - x0, wy1 = iy - y0, wz1 = iz - z0;
        float wx0 = 1.f - wx1, wy0 = 1.f - wy1, wz0 = 1.f - wz1;

        float w8[8];
        int off8[8];
#pragma unroll
        for (int k = 0; k < 8; ++k) {
            float xf = x0 + (float)(k & 1);
            float yf = y0 + (float)((k >> 1) & 1);
            float zf = z0 + (float)(k >> 2);
            bool valid = (xf >= 0.f) & (xf <= 99.f) &
                         (yf >= 0.f) & (yf <= 7.f) &
                         (zf >= 0.f) & (zf <= 99.f);
            int xi = (int)fminf(fmaxf(xf, 0.f), 99.f);
            int yi = (int)fminf(fmaxf(yf, 0.f), 7.f);
            int zi = (int)fminf(fmaxf(zf, 0.f), 99.f);
            float w = ((k & 1) ? wx1 : wx0) * (((k >> 1) & 1) ? wy1 : wy0) *
                      ((k >> 2) ? wz1 : wz0);
            w8[k] = valid ? w : 0.f;
            off8[k] = (zi * GZ + yi) * GY + xi;  // voxel index in [vid] space
        }

        const unsigned short* hb = h + (size_t)(b * NT + t) * NVOX * OC;
        float sval[OC];
#pragma unroll
        for (int o2 = 0; o2 < OC; ++o2) sval[o2] = 0.f;
#pragma unroll
        for (int k = 0; k < 8; ++k) {
            float w = w8[k];
            const uint4* cp =
                reinterpret_cast<const uint4*>(hb + (size_t)off8[k] * OC);
            uint4 a0 = cp[0], a1 = cp[1], a2 = cp[2], a3 = cp[3], a4 = cp[4];
            unsigned int uu[20] = {a0.x, a0.y, a0.z, a0.w, a1.x, a1.y, a1.z, a1.w,
                                   a2.x, a2.y, a2.z, a2.w, a3.x, a3.y, a3.z, a3.w,
                                   a4.x, a4.y, a4.z, a4.w};
#pragma unroll
            for (int j = 0; j < 20; ++j) {
                sval[2 * j + 0] = fmaf(w, bf_lo(uu[j]), sval[2 * j + 0]);
                sval[2 * j + 1] = fmaf(w, bf_hi(uu[j]), sval[2 * j + 1]);
            }
        }

        // acc[o] += W_T[o, t*40 + o2] * sval[o2]
#pragma unroll
        for (int o = 0; o < OC; ++o) {
            const float4* w4 =
                reinterpret_cast<const float4*>(W_T + o * (NT * OC) + t * OC);
#pragma unroll
            for (int q = 0; q < 10; ++q) {
                float4 w = w4[q];
                acc[o] = fmaf(w.x, sval[4 * q + 0], acc[o]);
                acc[o] = fmaf(w.y, sval[4 * q + 1], acc[o]);
                acc[o] = fmaf(w.z, sval[4 * q + 2], acc[o]);
                acc[o] = fmaf(w.w, sval[4 * q + 3], acc[o]);
            }
        }
    }

    // ---- t = 2: identity grid -> exact pass-through (single 80B load) ----
    {
        const uint4* cp = reinterpret_cast<const uint4*>(
            h + ((size_t)(b * NT + 2) * NVOX + (size_t)vid) * OC);
        uint4 a0 = cp[0], a1 = cp[1], a2 = cp[2], a3 = cp[3], a4 = cp[4];
        unsigned int uu[20] = {a0.x, a0.y, a0.z, a0.w, a1.x, a1.y, a1.z, a1.w,
                               a2.x, a2.y, a2.z, a2.w, a3.x, a3.y, a3.z, a3.w,
                               a4.x, a4.y, a4.z, a4.w};
        float sval[OC];
#pragma unroll
        for (int j = 0; j < 20; ++j) {
            sval[2 * j + 0] = bf_lo(uu[j]);
            sval[2 * j + 1] = bf_hi(uu[j]);
        }
#pragma unroll
        for (int o = 0; o < OC; ++o) {
            const float4* w4 =
                reinterpret_cast<const float4*>(W_T + o * (NT * OC) + 2 * OC);
#pragma unroll
            for (int q = 0; q < 10; ++q) {
                float4 w = w4[q];
                acc[o] = fmaf(w.x, sval[4 * q + 0], acc[o]);
                acc[o] = fmaf(w.y, sval[4 * q + 1], acc[o]);
                acc[o] = fmaf(w.z, sval[4 * q + 2], acc[o]);
                acc[o] = fmaf(w.w, sval[4 * q + 3], acc[o]);
            }
        }
    }

    // per-o planes: lanes have consecutive vid -> coalesced per o
    float* op = out + (size_t)b * OC * NVOX + vid;
#pragma unroll
    for (int o = 0; o < OC; ++o) op[(size_t)o * NVOX] = fmaxf(acc[o], 0.f);
}

extern "C" void kernel_launch(void* const* d_in, const int* in_sizes, int n_in,
                              void* d_out, int out_size, void* d_ws, size_t ws_size,
                              hipStream_t stream) {
    const float* frustum = (const float*)d_in[0];
    const float* RT      = (const float*)d_in[1];
    const float* intrins = (const float*)d_in[2];
    const float* DoF     = (const float*)d_in[3];
    const float* W_N     = (const float*)d_in[4];
    const float* b_N     = (const float*)d_in[5];
    const float* W_T     = (const float*)d_in[6];
    const float* b_T     = (const float*)d_in[7];
    float* out = (float*)d_out;

    const size_t ft_bytes = FT_ELEMS * sizeof(unsigned short); // ~85 MB
    const size_t h_bytes  = HSZ * sizeof(unsigned short);      // ~38.4 MB
    const size_t small = 4096;                                 // P + theta

    char* base = (char*)d_ws;
    bool use_ft = ws_size >= ft_bytes + h_bytes + small;

    size_t ft_al = use_ft ? ((ft_bytes + 255) & ~(size_t)255) : 0;
    unsigned short* ft_buf = (unsigned short*)base;
    unsigned short* h_buf = (unsigned short*)(base + ft_al);
    float* P_buf = (float*)(base + ft_al + ((h_bytes + 255) & ~(size_t)255));
    float* th_buf = P_buf + NB * NT * NCAM * 12;

    setup_kernel<<<1, 128, 0, stream>>>(RT, intrins, DoF, P_buf, th_buf);

    const int tr_blocks = (NB * NT * NCAM * FSZ) / 256;  // 10368
    const int n1_blocks = (NB * NT * NVOX) / 256;        // 1875
    const int n2_blocks = (NB * NVOX) / 256;             // 625

    if (use_ft) {
        transpose_feat<<<tr_blocks, 256, 0, stream>>>(frustum, ft_buf);
        sample_mlp1<true><<<n1_blocks, 256, 0, stream>>>(
            frustum, ft_buf, P_buf, W_N, b_N, h_buf);
    } else {
        sample_mlp1<false><<<n1_blocks, 256, 0, stream>>>(
            frustum, (const unsigned short*)nullptr, P_buf, W_N, b_N, h_buf);
    }

    warp_mlp2<<<n2_blocks, 256, 0, stream>>>(h_buf, th_buf, W_T, b_T, out);
}

// Round 3
// 459.746 us; speedup vs baseline: 1.4766x; 1.2559x over previous
//
#include <hip/hip_runtime.h>

// ---- problem constants (from reference) ----
#define NB 2
#define NT 3
#define NCAM 6
#define NC 16
#define FD 48
#define FH 24
#define FW 64
#define GX 100
#define GY 100
#define GZ 8
#define OC 40
#define NVOX (GX * GY * GZ)          // 80000  (divisible by 64 -> bt, b wave-uniform)
#define FSZ (FD * FH * FW)           // 73728 voxels per channel volume
#define CAMSZ (NC * FSZ)             // per-camera feature volume (orig layout)
#define BTSZ (NCAM * CAMSZ)          // per-(b,t) feature block (orig layout)
#define HSZ ((size_t)NB * NT * OC * NVOX)             // 19,200,000 elems
#define FT_ELEMS ((size_t)NB * NT * NCAM * FSZ * NC)  // 42,467,328

static __device__ __forceinline__ unsigned short f2bf_rne(float x) {
    unsigned int u = __float_as_uint(x);
    unsigned int r = (u + 0x7fffu + ((u >> 16) & 1u)) >> 16;
    return (unsigned short)r;
}
static __device__ __forceinline__ float bf_lo(unsigned int u) {
    return __uint_as_float(u << 16);
}
static __device__ __forceinline__ float bf_hi(unsigned int u) {
    return __uint_as_float(u & 0xffff0000u);
}

// ----------------------------------------------------------------------------
// Setup math (device helper): P[b,t,n] = intrins[b] @ RT[b,t,n][:3,:]  (3x4)
// theta[b,t] cumulative affine (3x4): t=2 -> I, t=1 -> M4[b,1],
// t=0 -> M4[b,0] @ M4[b,1]
// ----------------------------------------------------------------------------
static __device__ __forceinline__ void do_setup(
    int tid, const float* __restrict__ RT, const float* __restrict__ intrins,
    const float* __restrict__ DoF, float* __restrict__ P,
    float* __restrict__ theta) {
    if (tid < NB * NT * NCAM) {
        int bt = tid / NCAM;
        int b = bt / NT;
        const float* I3 = intrins + b * 9;
        const float* R = RT + (size_t)tid * 16;
        float* Pp = P + tid * 12;
        for (int r = 0; r < 3; ++r)
            for (int c = 0; c < 4; ++c) {
                float s = 0.f;
                for (int k = 0; k < 3; ++k) s += I3[r * 3 + k] * R[k * 4 + c];
                Pp[r * 4 + c] = s;
            }
    }
    if (tid >= 64 && tid < 64 + NB) {
        int b = tid - 64;
        const float* D0 = DoF + (size_t)(b * NT + 0) * 16;
        const float* D1 = DoF + (size_t)(b * NT + 1) * 16;
        float* th = theta + (size_t)b * NT * 12;
        for (int i = 0; i < 12; ++i) th[2 * 12 + i] = 0.f;
        th[2 * 12 + 0] = 1.f; th[2 * 12 + 5] = 1.f; th[2 * 12 + 10] = 1.f;
        for (int i = 0; i < 12; ++i) th[1 * 12 + i] = D1[i];
        for (int r = 0; r < 3; ++r)
            for (int c = 0; c < 4; ++c) {
                float s = (c == 3) ? D0[r * 4 + 3] : 0.f;
                for (int k = 0; k < 3; ++k) s += D0[r * 4 + k] * D1[k * 4 + c];
                th[0 * 12 + r * 4 + c] = s;
            }
    }
}

__global__ void setup_kernel(const float* __restrict__ RT,
                             const float* __restrict__ intrins,
                             const float* __restrict__ DoF,
                             float* __restrict__ P,
                             float* __restrict__ theta) {
    do_setup(threadIdx.x, RT, intrins, DoF, P, theta);
}

// ----------------------------------------------------------------------------
// Transpose features (B,T,N,C,FD,FH,FW) -> [btn][pos][C16] channel-last
// (fp32 or bf16 output). Block 0 additionally performs setup (fused dispatch;
// sample_mlp1 only launches after this kernel completes, so P/theta are ready).
// ----------------------------------------------------------------------------
template <typename FT>
__global__ __launch_bounds__(256) void transpose_feat(
    const float* __restrict__ feat, FT* __restrict__ ft,
    const float* __restrict__ RT, const float* __restrict__ intrins,
    const float* __restrict__ DoF, float* __restrict__ P,
    float* __restrict__ theta) {
    if (blockIdx.x == 0) do_setup(threadIdx.x, RT, intrins, DoF, P, theta);
    size_t tid = (size_t)blockIdx.x * 256 + threadIdx.x;
    int pos = (int)(tid % FSZ);
    int btn = (int)(tid / FSZ);
    const float* src = feat + (size_t)btn * CAMSZ + pos;
    float v[NC];
#pragma unroll
    for (int c = 0; c < NC; ++c) v[c] = src[(size_t)c * FSZ];
    if constexpr (sizeof(FT) == 4) {
        float4* dst = reinterpret_cast<float4*>(
            (float*)ft + ((size_t)btn * FSZ + pos) * NC);
#pragma unroll
        for (int q = 0; q < 4; ++q)
            dst[q] = make_float4(v[4 * q], v[4 * q + 1], v[4 * q + 2], v[4 * q + 3]);
    } else {
        unsigned int packed[8];
#pragma unroll
        for (int j = 0; j < 8; ++j)
            packed[j] = (unsigned int)f2bf_rne(v[2 * j]) |
                        ((unsigned int)f2bf_rne(v[2 * j + 1]) << 16);
        uint4* dst = reinterpret_cast<uint4*>(
            (unsigned short*)ft + ((size_t)btn * FSZ + pos) * NC);
        dst[0] = make_uint4(packed[0], packed[1], packed[2], packed[3]);
        dst[1] = make_uint4(packed[4], packed[5], packed[6], packed[7]);
    }
}

// ----------------------------------------------------------------------------
// Kernel 1: frustum trilinear sample (6 cams x 16 ch) + W_N matvec + ReLU -> h
// ROUND-0 STRUCTURE (one thread per (b,t,voxel), sequential 6-cam loop,
// fp32 float4 gather -- bf16 gather regressed: VALU unpack doubled VALUBusy).
// NEW: per-cam validity early-out. All 6 cams share ~the same pose (base_rt +
// 0.02 noise), so ~75% of voxels are outside EVERY cam's frustum (x<2 or
// |y|>x wedge) -> their gathers+matvecs are pure zeros and are skipped.
// Waves span 64 consecutive gy at fixed (gx,gz), so skipping is largely
// wave-coherent (s_cbranch_execz skips the loads entirely).
// h layout: [bt][vid][OC] bf16  (vid = gx*GZ*GY + gz*GY + gy)
// ----------------------------------------------------------------------------
template <typename FT, bool CHLAST>
__global__ __launch_bounds__(256) void sample_mlp1(
    const float* __restrict__ feat,   // original layout (used when !CHLAST)
    const FT* __restrict__ ft,        // channel-last (used when CHLAST)
    const float* __restrict__ P,
    const float* __restrict__ W_N,
    const float* __restrict__ b_N,
    unsigned short* __restrict__ h) {
    int tid = blockIdx.x * 256 + threadIdx.x;
    int vid = tid % NVOX;
    int bt = __builtin_amdgcn_readfirstlane(tid / NVOX);  // wave-uniform (NVOX%64==0)
    int gy = vid % GY;
    int r2 = vid / GY;
    int gz = r2 % GZ;
    int gx = r2 / GZ;
    float X = (float)gx - 49.5f;
    float Y = (float)gy - 49.5f;
    float Z = (float)gz - 2.5f;

    float acc[OC];
#pragma unroll
    for (int o = 0; o < OC; ++o) acc[o] = b_N[o];

    for (int n = 0; n < NCAM; ++n) {
        const float* Pp = P + (bt * NCAM + n) * 12;
        float px = Pp[0] * X + Pp[1] * Y + Pp[2] * Z + Pp[3];
        float py = Pp[4] * X + Pp[5] * Y + Pp[6] * Z + Pp[7];
        float pz = Pp[8] * X + Pp[9] * Y + Pp[10] * Z + Pp[11];
        float zc = fmaxf(pz, 1e-5f);
        float ix = px / zc;                       // = u (normalization round-trips)
        float iy = py / zc;
        float iz = (pz - 2.0f) * (48.0f / 44.8f); // = dbin

        // exact early-out: outside the open box, every corner weight is zero
        bool cam_valid = (ix > -1.f) & (ix < (float)FW) &
                         (iy > -1.f) & (iy < (float)FH) &
                         (iz > -1.f) & (iz < (float)FD);
        if (!cam_valid) continue;

        float x0 = floorf(ix), y0 = floorf(iy), z0 = floorf(iz);
        float wx1 = ix - x0, wy1 = iy - y0, wz1 = iz - z0;
        float wx0 = 1.f - wx1, wy0 = 1.f - wy1, wz0 = 1.f - wz1;

        float w8[8];
        int off8[8];
#pragma unroll
        for (int k = 0; k < 8; ++k) {
            float xf = x0 + (float)(k & 1);
            float yf = y0 + (float)((k >> 1) & 1);
            float zf = z0 + (float)(k >> 2);
            bool valid = (xf >= 0.f) & (xf <= (float)(FW - 1)) &
                         (yf >= 0.f) & (yf <= (float)(FH - 1)) &
                         (zf >= 0.f) & (zf <= (float)(FD - 1));
            int xi = (int)fminf(fmaxf(xf, 0.f), (float)(FW - 1));
            int yi = (int)fminf(fmaxf(yf, 0.f), (float)(FH - 1));
            int zi = (int)fminf(fmaxf(zf, 0.f), (float)(FD - 1));
            float w = ((k & 1) ? wx1 : wx0) * (((k >> 1) & 1) ? wy1 : wy0) *
                      ((k >> 2) ? wz1 : wz0);
            w8[k] = valid ? w : 0.f;
            off8[k] = (zi * FH + yi) * FW + xi;
        }

        float s[NC];
#pragma unroll
        for (int c = 0; c < NC; ++c) s[c] = 0.f;

        if constexpr (CHLAST) {
            const size_t camBase = (size_t)(bt * NCAM + n) * FSZ;
            if constexpr (sizeof(FT) == 4) {
#pragma unroll
                for (int k = 0; k < 8; ++k) {
                    float w = w8[k];
                    const float4* cp = reinterpret_cast<const float4*>(
                        (const float*)ft + (camBase + (size_t)off8[k]) * NC);
#pragma unroll
                    for (int q = 0; q < 4; ++q) {
                        float4 v = cp[q];
                        s[4 * q + 0] = fmaf(w, v.x, s[4 * q + 0]);
                        s[4 * q + 1] = fmaf(w, v.y, s[4 * q + 1]);
                        s[4 * q + 2] = fmaf(w, v.z, s[4 * q + 2]);
                        s[4 * q + 3] = fmaf(w, v.w, s[4 * q + 3]);
                    }
                }
            } else {
#pragma unroll
                for (int k = 0; k < 8; ++k) {
                    float w = w8[k];
                    const uint4* cp = reinterpret_cast<const uint4*>(
                        (const unsigned short*)ft + (camBase + (size_t)off8[k]) * NC);
                    uint4 a = cp[0], b2 = cp[1];
                    unsigned int uu[8] = {a.x, a.y, a.z, a.w, b2.x, b2.y, b2.z, b2.w};
#pragma unroll
                    for (int j = 0; j < 8; ++j) {
                        s[2 * j + 0] = fmaf(w, bf_lo(uu[j]), s[2 * j + 0]);
                        s[2 * j + 1] = fmaf(w, bf_hi(uu[j]), s[2 * j + 1]);
                    }
                }
            }
        } else {
            const float* fn = feat + (size_t)bt * BTSZ + (size_t)n * CAMSZ;
#pragma unroll
            for (int c = 0; c < NC; ++c) {
                const float* fc = fn + (size_t)c * FSZ;
                float v = 0.f;
#pragma unroll
                for (int k = 0; k < 8; ++k) v = fmaf(w8[k], fc[off8[k]], v);
                s[c] = v;
            }
        }

        // acc[o] += W_N[o, n*16 + c] * s[c]
#pragma unroll
        for (int o = 0; o < OC; ++o) {
            const float4* w4 =
                reinterpret_cast<const float4*>(W_N + o * (NCAM * NC) + n * NC);
#pragma unroll
            for (int q = 0; q < 4; ++q) {
                float4 w = w4[q];
                acc[o] = fmaf(w.x, s[4 * q + 0], acc[o]);
                acc[o] = fmaf(w.y, s[4 * q + 1], acc[o]);
                acc[o] = fmaf(w.z, s[4 * q + 2], acc[o]);
                acc[o] = fmaf(w.w, s[4 * q + 3], acc[o]);
            }
        }
    }

    // ReLU + pack to bf16, store 80B (5 x uint4)
    unsigned int u[20];
#pragma unroll
    for (int j = 0; j < 20; ++j)
        u[j] = (unsigned int)f2bf_rne(fmaxf(acc[2 * j], 0.f)) |
               ((unsigned int)f2bf_rne(fmaxf(acc[2 * j + 1], 0.f)) << 16);
    uint4* d4 = reinterpret_cast<uint4*>(
        h + ((size_t)bt * NVOX + (size_t)vid) * OC);
#pragma unroll
    for (int q = 0; q < 5; ++q)
        d4[q] = make_uint4(u[4 * q], u[4 * q + 1], u[4 * q + 2], u[4 * q + 3]);
}

// ----------------------------------------------------------------------------
// Kernel 2: temporal affine warp (trilinear on bf16 channel-last h) + W_T + ReLU
// One thread per (b,voxel), sequential t loop. t=2 has theta == I (identity
// grid, align_corners) -> exact pass-through: single 80B load, no gather.
// out layout: [b][o][d][h][w] = (B,40,100,8,100)
// ----------------------------------------------------------------------------
__global__ __launch_bounds__(256) void warp_mlp2(
    const unsigned short* __restrict__ h,
    const float* __restrict__ theta,
    const float* __restrict__ W_T,
    const float* __restrict__ b_T,
    float* __restrict__ out) {
    int tid = blockIdx.x * 256 + threadIdx.x;
    int vid = tid % NVOX;
    int b = __builtin_amdgcn_readfirstlane(tid / NVOX);  // wave-uniform
    int w_ = vid % GY;        // Wp = 100
    int r2 = vid / GY;
    int h_ = r2 % GZ;         // Hp = 8
    int d_ = r2 / GZ;         // Dp = 100

    float xg = -1.f + 2.f * (float)w_ / 99.f;
    float yg = -1.f + 2.f * (float)h_ / 7.f;
    float zg = -1.f + 2.f * (float)d_ / 99.f;

    float acc[OC];
#pragma unroll
    for (int o = 0; o < OC; ++o) acc[o] = b_T[o];

    // ---- t = 0, 1: full trilinear gather ----
    for (int t = 0; t < 2; ++t) {
        const float* th = theta + (b * NT + t) * 12;
        float g0 = th[0] * xg + th[1] * yg + th[2] * zg + th[3];
        float g1 = th[4] * xg + th[5] * yg + th[6] * zg + th[7];
        float g2 = th[8] * xg + th[9] * yg + th[10] * zg + th[11];
        float ix = (g0 + 1.f) * 0.5f * 99.f;
        float iy = (g1 + 1.f) * 0.5f * 7.f;
        float iz = (g2 + 1.f) * 0.5f * 99.f;
        float x0 = floorf(ix), y0 = floorf(iy), z0 = floorf(iz);
        float wx1 = ix - x0, wy1 = iy - y0, wz1 = iz - z0;
        float wx0 = 1.f - wx1, wy0 = 1.f - wy1, wz0 = 1.f - wz1;

        float w8[8];
        int off8[8];
#pragma unroll
        for (int k = 0; k < 8; ++k) {
            float xf = x0 + (float)(k & 1);
            float yf = y0 + (float)((k >> 1) & 1);
            float zf = z0 + (float)(k >> 2);
            bool valid = (xf >= 0.f) & (xf <= 99.f) &
                         (yf >= 0.f) & (yf <= 7.f) &
                         (zf >= 0.f) & (zf <= 99.f);
            int xi = (int)fminf(fmaxf(xf, 0.f), 99.f);
            int yi = (int)fminf(fmaxf(yf, 0.f), 7.f);
            int zi = (int)fminf(fmaxf(zf, 0.f), 99.f);
            float w = ((k & 1) ? wx1 : wx0) * (((k >> 1) & 1) ? wy1 : wy0) *
                      ((k >> 2) ? wz1 : wz0);
            w8[k] = valid ? w : 0.f;
            off8[k] = (zi * GZ + yi) * GY + xi;  // voxel index in [vid] space
        }

        const unsigned short* hb = h + (size_t)(b * NT + t) * NVOX * OC;
        float sval[OC];
#pragma unroll
        for (int o2 = 0; o2 < OC; ++o2) sval[o2] = 0.f;
#pragma unroll
        for (int k = 0; k < 8; ++k) {
            float w = w8[k];
            const uint4* cp =
                reinterpret_cast<const uint4*>(hb + (size_t)off8[k] * OC);
            uint4 a0 = cp[0], a1 = cp[1], a2 = cp[2], a3 = cp[3], a4 = cp[4];
            unsigned int uu[20] = {a0.x, a0.y, a0.z, a0.w, a1.x, a1.y, a1.z, a1.w,
                                   a2.x, a2.y, a2.z, a2.w, a3.x, a3.y, a3.z, a3.w,
                                   a4.x, a4.y, a4.z, a4.w};
#pragma unroll
            for (int j = 0; j < 20; ++j) {
                sval[2 * j + 0] = fmaf(w, bf_lo(uu[j]), sval[2 * j + 0]);
                sval[2 * j + 1] = fmaf(w, bf_hi(uu[j]), sval[2 * j + 1]);
            }
        }

        // acc[o] += W_T[o, t*40 + o2] * sval[o2]
#pragma unroll
        for (int o = 0; o < OC; ++o) {
            const float4* w4 =
                reinterpret_cast<const float4*>(W_T + o * (NT * OC) + t * OC);
#pragma unroll
            for (int q = 0; q < 10; ++q) {
                float4 w = w4[q];
                acc[o] = fmaf(w.x, sval[4 * q + 0], acc[o]);
                acc[o] = fmaf(w.y, sval[4 * q + 1], acc[o]);
                acc[o] = fmaf(w.z, sval[4 * q + 2], acc[o]);
                acc[o] = fmaf(w.w, sval[4 * q + 3], acc[o]);
            }
        }
    }

    // ---- t = 2: identity grid -> exact pass-through (single 80B load) ----
    {
        const uint4* cp = reinterpret_cast<const uint4*>(
            h + ((size_t)(b * NT + 2) * NVOX + (size_t)vid) * OC);
        uint4 a0 = cp[0], a1 = cp[1], a2 = cp[2], a3 = cp[3], a4 = cp[4];
        unsigned int uu[20] = {a0.x, a0.y, a0.z, a0.w, a1.x, a1.y, a1.z, a1.w,
                               a2.x, a2.y, a2.z, a2.w, a3.x, a3.y, a3.z, a3.w,
                               a4.x, a4.y, a4.z, a4.w};
        float sval[OC];
#pragma unroll
        for (int j = 0; j < 20; ++j) {
            sval[2 * j + 0] = bf_lo(uu[j]);
            sval[2 * j + 1] = bf_hi(uu[j]);
        }
#pragma unroll
        for (int o = 0; o < OC; ++o) {
            const float4* w4 =
                reinterpret_cast<const float4*>(W_T + o * (NT * OC) + 2 * OC);
#pragma unroll
            for (int q = 0; q < 10; ++q) {
                float4 w = w4[q];
                acc[o] = fmaf(w.x, sval[4 * q + 0], acc[o]);
                acc[o] = fmaf(w.y, sval[4 * q + 1], acc[o]);
                acc[o] = fmaf(w.z, sval[4 * q + 2], acc[o]);
                acc[o] = fmaf(w.w, sval[4 * q + 3], acc[o]);
            }
        }
    }

    // per-o planes: lanes have consecutive vid -> coalesced per o
    float* op = out + (size_t)b * OC * NVOX + vid;
#pragma unroll
    for (int o = 0; o < OC; ++o) op[(size_t)o * NVOX] = fmaxf(acc[o], 0.f);
}

extern "C" void kernel_launch(void* const* d_in, const int* in_sizes, int n_in,
                              void* d_out, int out_size, void* d_ws, size_t ws_size,
                              hipStream_t stream) {
    const float* frustum = (const float*)d_in[0];
    const float* RT      = (const float*)d_in[1];
    const float* intrins = (const float*)d_in[2];
    const float* DoF     = (const float*)d_in[3];
    const float* W_N     = (const float*)d_in[4];
    const float* b_N     = (const float*)d_in[5];
    const float* W_T     = (const float*)d_in[6];
    const float* b_T     = (const float*)d_in[7];
    float* out = (float*)d_out;

    const size_t ft_f32  = FT_ELEMS * sizeof(float);          // ~170 MB
    const size_t ft_bf16 = FT_ELEMS * sizeof(unsigned short); // ~85 MB
    const size_t h_bytes = HSZ * sizeof(unsigned short);      // ~38.4 MB
    const size_t small = 4096;                                // P + theta

    char* base = (char*)d_ws;
    int mode;  // 0 = fp32 chlast, 1 = bf16 chlast, 2 = no transpose
    size_t ft_bytes;
    if (ws_size >= ft_f32 + h_bytes + small) { mode = 0; ft_bytes = ft_f32; }
    else if (ws_size >= ft_bf16 + h_bytes + small) { mode = 1; ft_bytes = ft_bf16; }
    else { mode = 2; ft_bytes = 0; }

    size_t ft_al = (ft_bytes + 255) & ~(size_t)255;
    void* ft_buf = base;
    unsigned short* h_buf = (unsigned short*)(base + ft_al);
    float* P_buf = (float*)(base + ft_al + ((h_bytes + 255) & ~(size_t)255));
    float* th_buf = P_buf + NB * NT * NCAM * 12;

    const int tr_blocks = (NB * NT * NCAM * FSZ) / 256;  // 10368
    const int n1_blocks = (NB * NT * NVOX) / 256;        // 1875
    const int n2_blocks = (NB * NVOX) / 256;             // 625

    if (mode == 0) {
        transpose_feat<float><<<tr_blocks, 256, 0, stream>>>(
            frustum, (float*)ft_buf, RT, intrins, DoF, P_buf, th_buf);
        sample_mlp1<float, true><<<n1_blocks, 256, 0, stream>>>(
            frustum, (const float*)ft_buf, P_buf, W_N, b_N, h_buf);
    } else if (mode == 1) {
        transpose_feat<unsigned short><<<tr_blocks, 256, 0, stream>>>(
            frustum, (unsigned short*)ft_buf, RT, intrins, DoF, P_buf, th_buf);
        sample_mlp1<unsigned short, true><<<n1_blocks, 256, 0, stream>>>(
            frustum, (const unsigned short*)ft_buf, P_buf, W_N, b_N, h_buf);
    } else {
        setup_kernel<<<1, 128, 0, stream>>>(RT, intrins, DoF, P_buf, th_buf);
        sample_mlp1<float, false><<<n1_blocks, 256, 0, stream>>>(
            frustum, (const float*)nullptr, P_buf, W_N, b_N, h_buf);
    }

    warp_mlp2<<<n2_blocks, 256, 0, stream>>>(h_buf, th_buf, W_T, b_T, out);
}